// Round 8
// baseline (793.537 us; speedup 1.0000x reference)
//
#include <hip/hip_runtime.h>
#include <math.h>

#define HID 256
#define STRIDE 20   // padded slot-words per k row (16 data + 4 pad) -> full 32-bank spread

// degree tables: d1[i]=1/sqrt(i+1) (GCN layers), d2[i]=1/sqrt(1+0.5i) (op conv)
__device__ __forceinline__ float d1c(int i) { return 1.0f / sqrtf((float)(i + 1)); }
__device__ __forceinline__ float d2c(int i) { return 1.0f / sqrtf(1.0f + 0.5f * (float)i); }

// in-place descending prefix mix: v[r] = sum_{i<=r} d1[i]*d1[r]*v[i]
__device__ __forceinline__ void mixA1_4(float (&v)[7][4]) {
#pragma unroll
    for (int r = 6; r >= 0; --r) {
        float t[4] = {0, 0, 0, 0};
#pragma unroll
        for (int i = 0; i <= r; ++i) {
            const float c = d1c(i) * d1c(r);
#pragma unroll
            for (int j = 0; j < 4; ++j) t[j] = fmaf(c, v[i][j], t[j]);
        }
#pragma unroll
        for (int j = 0; j < 4; ++j) v[r][j] = t[j];
    }
}
__device__ __forceinline__ void mixA1_8(float (&v)[7][8]) {
#pragma unroll
    for (int r = 6; r >= 0; --r) {
        float t[8] = {0, 0, 0, 0, 0, 0, 0, 0};
#pragma unroll
        for (int i = 0; i <= r; ++i) {
            const float c = d1c(i) * d1c(r);
#pragma unroll
            for (int j = 0; j < 8; ++j) t[j] = fmaf(c, v[i][j], t[j]);
        }
#pragma unroll
        for (int j = 0; j < 8; ++j) v[r][j] = t[j];
    }
}

// P^T[kk][16 slots + 4 pad], kk in [0,128). Logical chunk (2g+h) lives at
// phys = (2g+h) ^ key(kk), key = ((kk>>2)^(kk>>4))&3. Lane (g,L) stages its 4
// cols as kk = 4L..4L+3: key = (L^(L>>2))&3 covers all 4 values across lanes,
// and STRIDE=20 gives kk*20 mod 32 full spread -> stores ~conflict-free.
__device__ __forceinline__ void storePT4(float* shp, int g2, int L, const float (&v)[7][4]) {
    const int key = (L ^ (L >> 2)) & 3;
    const int pA  = (g2 ^ key) << 2;
    float* b0 = shp + STRIDE * 4 * L + pA;
    float* b1 = shp + STRIDE * 4 * L + (pA ^ 4);
#pragma unroll
    for (int j = 0; j < 4; ++j) {
        *(float4*)(b0 + STRIDE * j) = make_float4(v[0][j], v[1][j], v[2][j], v[3][j]);
        *(float4*)(b1 + STRIDE * j) = make_float4(v[4][j], v[5][j], v[6][j], 0.0f);
    }
}
__device__ __forceinline__ void storePT8(float* shp, int g2, int L,
                                         const float (&v)[7][8], int lo) {
    const int key = (L ^ (L >> 2)) & 3;
    const int pA  = (g2 ^ key) << 2;
    float* b0 = shp + STRIDE * 4 * L + pA;
    float* b1 = shp + STRIDE * 4 * L + (pA ^ 4);
#pragma unroll
    for (int j = 0; j < 4; ++j) {
        *(float4*)(b0 + STRIDE * j) = make_float4(v[0][lo + j], v[1][lo + j], v[2][lo + j], v[3][lo + j]);
        *(float4*)(b1 + STRIDE * j) = make_float4(v[4][lo + j], v[5][lo + j], v[6][lo + j], 0.0f);
    }
}

// acc[7][8] += P^T[kk][graph g rows] * W[kbase+kk][{c0a..+3, c0b..+3}], kk=0..127
__device__ __forceinline__ void gemm_half(float (&acc)[7][8], const float* __restrict__ wrow,
                                          const float* shp, int g2, int c0a, int c0b) {
#pragma unroll 2
    for (int t = 0; t < 32; ++t) {
        const int key = (t ^ (t >> 2)) & 3;
        const int pA  = (g2 ^ key) << 2;
        const int bas = t * (4 * STRIDE);
#pragma unroll
        for (int u = 0; u < 4; ++u) {
            float4 p0 = *(const float4*)(shp + bas + STRIDE * u + pA);
            float4 p1 = *(const float4*)(shp + bas + STRIDE * u + (pA ^ 4));
            const float* wk = wrow + (long)(4 * t + u) * HID;
            float4 w0 = *(const float4*)(wk + c0a);
            float4 w1 = *(const float4*)(wk + c0b);
            const float pr[7] = {p0.x, p0.y, p0.z, p0.w, p1.x, p1.y, p1.z};
#pragma unroll
            for (int r = 0; r < 7; ++r) {
                acc[r][0] = fmaf(pr[r], w0.x, acc[r][0]);
                acc[r][1] = fmaf(pr[r], w0.y, acc[r][1]);
                acc[r][2] = fmaf(pr[r], w0.z, acc[r][2]);
                acc[r][3] = fmaf(pr[r], w0.w, acc[r][3]);
                acc[r][4] = fmaf(pr[r], w1.x, acc[r][4]);
                acc[r][5] = fmaf(pr[r], w1.y, acc[r][5]);
                acc[r][6] = fmaf(pr[r], w1.z, acc[r][6]);
                acc[r][7] = fmaf(pr[r], w1.w, acc[r][7]);
            }
        }
    }
}

// Block = 64 threads = ONE WAVE = 2 graphs; lane owns cols {4L..4L+3, 128+4L..131+4L}.
// k-loops run in two 128-k halves over ONE 10 KB buffer (LDS wave-private, zero
// barriers; in-wave ds ordering covers all restage WARs). Layer-2 stages P2
// half A before acc2 is born -> register peak ~115 fits the pinned 128 budget.
// amdgpu_waves_per_eu(4,4): exact 4 waves/EU -> 128-VGPR allocation, stops the
// compiler's 6-wave/84-reg squeeze that spilled R5-R7.
// Identities: avg_scores==0.5 (2-way softmax rows sum to 1); A*(X@W)==(A*X)@W;
// deg1[j]=j+1, deg2[j]=1+0.5j (fixed 7-node upper-tri DAG).
__global__ __launch_bounds__(64)
__attribute__((amdgpu_waves_per_eu(4, 4)))
void nas_fused(const float* __restrict__ X,
               const float* __restrict__ W1, const float* __restrict__ b1,
               const float* __restrict__ W2, const float* __restrict__ b2,
               const float* __restrict__ Wm, const float* __restrict__ bm,
               const float* __restrict__ g_op,
               float* __restrict__ out)
{
    __shared__ float sh[128 * STRIDE];   // 10 KB

    const int cg  = threadIdx.x;         // 0..63
    const int g   = cg >> 5;             // graph-in-wave
    const int L   = cg & 31;             // lane-in-graph
    const int g2  = g << 1;
    const int c0a = L << 2;
    const int c0b = 128 + (L << 2);
    const long node0 = (long)blockIdx.x * 14 + g * 7;

    // ================= layer 1: acc = (A1*X) @ W1, two k-halves =================
    float acc[7][8];
#pragma unroll
    for (int r = 0; r < 7; ++r)
#pragma unroll
        for (int j = 0; j < 8; ++j) acc[r][j] = 0.0f;

    for (int half = 0; half < 2; ++half) {
        float v[7][4];
        const float* xp = X + node0 * HID + (half ? c0b : c0a);
#pragma unroll
        for (int i = 0; i < 7; ++i) {
            float4 t = *(const float4*)(xp + (long)i * HID);
            v[i][0] = t.x; v[i][1] = t.y; v[i][2] = t.z; v[i][3] = t.w;
        }
        mixA1_4(v);
        storePT4(sh, g2, L, v);
        gemm_half(acc, W1 + (long)(half * 128) * HID, sh, g2, c0a, c0b);
    }
    {   // +b1, relu
        float4 ba = *(const float4*)(b1 + c0a);
        float4 bb = *(const float4*)(b1 + c0b);
        const float bia[8] = {ba.x, ba.y, ba.z, ba.w, bb.x, bb.y, bb.z, bb.w};
#pragma unroll
        for (int r = 0; r < 7; ++r)
#pragma unroll
            for (int j = 0; j < 8; ++j)
                acc[r][j] = fmaxf(acc[r][j] + bia[j], 0.0f);
    }
    mixA1_8(acc);   // P2 = A1 * H1

    // ================= layer 2: acc2 = P2 @ W2, two k-halves =================
    float acc2[7][8];
#pragma unroll
    for (int r = 0; r < 7; ++r)
#pragma unroll
        for (int j = 0; j < 8; ++j) acc2[r][j] = 0.0f;

    storePT8(sh, g2, L, acc, 0);         // frees acc[.][0..3] before acc2 peaks
    gemm_half(acc2, W2, sh, g2, c0a, c0b);
    storePT8(sh, g2, L, acc, 4);         // acc fully dead after this
    gemm_half(acc2, W2 + (long)128 * HID, sh, g2, c0a, c0b);

    {   // +b2, relu
        float4 ba = *(const float4*)(b2 + c0a);
        float4 bb = *(const float4*)(b2 + c0b);
        const float bia[8] = {ba.x, ba.y, ba.z, ba.w, bb.x, bb.y, bb.z, bb.w};
#pragma unroll
        for (int r = 0; r < 7; ++r)
#pragma unroll
            for (int j = 0; j < 8; ++j)
                acc2[r][j] = fmaxf(acc2[r][j] + bia[j], 0.0f);
    }

    // ============ projection: op_emb partials via LDS-restaged H2 ============
    // lane (g, rr=L>>2, q=L&3), rr<7 active: s[p] = sum_{kk=q mod 4} H2[rr][k]*Wm[k][p]
    const int rr = L >> 2;
    const int q  = L & 3;
    const int gh = g2 + (rr >> 2);       // logical chunk of row rr
    const int w  = rr & 3;
    float s[5] = {0, 0, 0, 0, 0};

#pragma unroll
    for (int half = 0; half < 2; ++half) {
        storePT8(sh, g2, L, acc2, half * 4);   // all lanes stage their 4 cols
        if (rr < 7) {
            const float* wmb = Wm + (long)(half * 128) * 5;
            for (int t = 0; t < 32; ++t) {
                const int key = (t ^ (t >> 2)) & 3;
                const float h2 = sh[t * (4 * STRIDE) + STRIDE * q + ((gh ^ key) << 2) + w];
                const float* wm = wmb + (long)(4 * t + q) * 5;
                s[0] = fmaf(h2, wm[0], s[0]);
                s[1] = fmaf(h2, wm[1], s[1]);
                s[2] = fmaf(h2, wm[2], s[2]);
                s[3] = fmaf(h2, wm[3], s[3]);
                s[4] = fmaf(h2, wm[4], s[4]);
            }
        }
    }
    // reduce over q (lanes rr*4+q differ in low 2 bits)
#pragma unroll
    for (int p = 0; p < 5; ++p) s[p] += __shfl_xor(s[p], 1, 64);
#pragma unroll
    for (int p = 0; p < 5; ++p) s[p] += __shfl_xor(s[p], 2, 64);

    // gather all 7 rows' logits (from lanes g*32 + i*4) + A2 mix, in registers
    float op[5];
#pragma unroll
    for (int p = 0; p < 5; ++p) op[p] = bm[p];
    const float d2r = d2c(L & 7);        // valid for L<7 (only those lanes use it)
#pragma unroll
    for (int i = 0; i < 7; ++i) {
        const int src = (cg & 32) + (i << 2);
        float t0 = __shfl(s[0], src, 64);
        float t1 = __shfl(s[1], src, 64);
        float t2 = __shfl(s[2], src, 64);
        float t3 = __shfl(s[3], src, 64);
        float t4 = __shfl(s[4], src, 64);
        // A2 weight for node L: self-loop d2r^2; incoming (i<L) 0.5*d2[i]*d2r; else 0
        const float wgt = (i > L) ? 0.0f
                        : (((i < L) ? 0.5f : 1.0f) * d2c(i) * d2r);
        op[0] = fmaf(wgt, t0, op[0]);
        op[1] = fmaf(wgt, t1, op[1]);
        op[2] = fmaf(wgt, t2, op[2]);
        op[3] = fmaf(wgt, t3, op[3]);
        op[4] = fmaf(wgt, t4, op[4]);
    }

    if (L < 7) {   // lane L finalizes node node0+L: + gumbel, hard argmax one-hot
        const float* gp = g_op + (node0 + L) * 5;
        float best = op[0] + gp[0];
        int bi = 0;
#pragma unroll
        for (int p = 1; p < 5; ++p) {
            float u = op[p] + gp[p];
            if (u > best) { best = u; bi = p; }   // strict > == jnp.argmax first-max
        }
        float* o = out + (node0 + L) * 5;
#pragma unroll
        for (int p = 0; p < 5; ++p) o[p] = (p == bi) ? 1.0f : 0.0f;
    }
}

extern "C" void kernel_launch(void* const* d_in, const int* in_sizes, int n_in,
                              void* d_out, int out_size, void* d_ws, size_t ws_size,
                              hipStream_t stream)
{
    const float* X   = (const float*)d_in[0];
    // d_in[1] edge_index, d_in[2] batch: compile-time-constant structure
    const float* W1  = (const float*)d_in[3];
    const float* b1  = (const float*)d_in[4];
    const float* W2  = (const float*)d_in[5];
    const float* b2  = (const float*)d_in[6];
    // d_in[7] We, d_in[8] be, d_in[11] g_edge: dead (avg_scores == 0.5)
    const float* Wm  = (const float*)d_in[9];
    const float* bm  = (const float*)d_in[10];
    const float* gop = (const float*)d_in[12];
    float* out = (float*)d_out;

    const int N       = in_sizes[0] / HID;  // 140000 nodes
    const int ngraph  = N / 7;              // 20000
    const int nblocks = ngraph / 2;         // 10000 one-wave blocks, 2 graphs each

    nas_fused<<<nblocks, 64, 0, stream>>>(X, W1, b1, W2, b2, Wm, bm, gop, out);
}

// Round 9
// 791.953 us; speedup vs baseline: 1.0020x; 1.0020x over previous
//
#include <hip/hip_runtime.h>
#include <math.h>

#define HID 256

// degree tables: d1[i]=1/sqrt(i+1) (GCN layers), d2[i]=1/sqrt(1+0.5i) (op conv)
__device__ __forceinline__ float d1c(int i) { return 1.0f / sqrtf((float)(i + 1)); }
__device__ __forceinline__ float d2c(int i) { return 1.0f / sqrtf(1.0f + 0.5f * (float)i); }

// in-place descending prefix mix: v[r] = sum_{i<=r} d1[i]*d1[r]*v[i]
__device__ __forceinline__ void mixA1(float (&v)[7][4]) {
#pragma unroll
    for (int r = 6; r >= 0; --r) {
        float t[4] = {0, 0, 0, 0};
#pragma unroll
        for (int i = 0; i <= r; ++i) {
            const float c = d1c(i) * d1c(r);
#pragma unroll
            for (int j = 0; j < 4; ++j) t[j] = fmaf(c, v[i][j], t[j]);
        }
#pragma unroll
        for (int j = 0; j < 4; ++j) v[r][j] = t[j];
    }
}

// P^T[k][32 slots]: logical 4-float chunk (2g+h) (h=0: rows 0-3, h=1: rows
// 4-6+pad) lives at phys = (2g+h) ^ ((k>>3)&7). Bijective per k -> each
// wave's region is private (zero barriers). Lane L stages its 4 cols as
// k = 4L..4L+3; all share key (L>>1)&7 == (k>>3)&7.
__device__ __forceinline__ void storePT(const float (&v)[7][4], float* shp, int g2, int L) {
    const int p0 = (g2 ^ ((L >> 1) & 7)) << 2;
    float* base = shp + (L << 7);            // k=4L -> word 4L*32
#pragma unroll
    for (int j = 0; j < 4; ++j) {
        const int a0 = (j << 5) + p0;
        *(float4*)(base + a0)       = make_float4(v[0][j], v[1][j], v[2][j], v[3][j]);
        *(float4*)(base + (a0 ^ 4)) = make_float4(v[4][j], v[5][j], v[6][j], 0.0f);
    }
}

// acc[7][4] += P^T[k][graph g rows] (single-address broadcast reads)
//            * W[k][c0..c0+3], k = 0..255
__device__ __forceinline__ void gemm_k(float (&acc)[7][4], const float* __restrict__ wb,
                                       const float* shp, int g2) {
    for (int k0 = 0; k0 < HID; k0 += 8) {
        const int p0 = (g2 ^ ((k0 >> 3) & 7)) << 2;   // key constant over the 8-k block
        const float* pbase = shp + (k0 << 5);
#pragma unroll
        for (int kk = 0; kk < 8; ++kk) {
            const int a0 = (kk << 5) + p0;
            float4 pa = *(const float4*)(pbase + a0);
            float4 pb = *(const float4*)(pbase + (a0 ^ 4));
            float4 w  = *(const float4*)(wb + (long)(k0 + kk) * HID);
            const float pr[7] = {pa.x, pa.y, pa.z, pa.w, pb.x, pb.y, pb.z};
#pragma unroll
            for (int r = 0; r < 7; ++r) {
                acc[r][0] = fmaf(pr[r], w.x, acc[r][0]);
                acc[r][1] = fmaf(pr[r], w.y, acc[r][1]);
                acc[r][2] = fmaf(pr[r], w.z, acc[r][2]);
                acc[r][3] = fmaf(pr[r], w.w, acc[r][3]);
            }
        }
    }
}

// 256 threads = 4 waves; WAVE = GRAPH (7 rows x 256 cols, 4 cols/lane).
// Zero __syncthreads: LDS regions are wave-private (per-k bijective swizzle);
// the P2 restage WAR is covered by in-wave ds ordering.
// Live set: k-loop ~60 regs, epilogue acc(28)+pm(35) ~70 -> fits the
// allocator's 5-wave/SIMD target (<=102 regs) without spilling; LDS 32 KB
// caps 5 blocks x 4 waves = 20 waves/CU (62.5%).
// Identities: avg_scores==0.5 (2-way softmax rows sum to 1); A*(X@W)==(A*X)@W;
// deg1[j]=j+1, deg2[j]=1+0.5j (fixed 7-node upper-tri DAG).
__global__ __launch_bounds__(256, 2)
void nas_fused(const float* __restrict__ X,
               const float* __restrict__ W1, const float* __restrict__ b1,
               const float* __restrict__ W2, const float* __restrict__ b2,
               const float* __restrict__ Wm, const float* __restrict__ bm,
               const float* __restrict__ g_op,
               float* __restrict__ out)
{
    __shared__ float sh[HID * 32];   // 32 KB: P^T[k][32 slots], 8 per graph

    const int tid = threadIdx.x;
    const int g   = tid >> 6;        // wave == graph-in-block, 0..3
    const int L   = tid & 63;        // lane, owns cols 4L..4L+3
    const int g2  = g << 1;
    const int c0  = L << 2;
    const long node0 = (long)blockIdx.x * 28 + g * 7;

    // ---------- stage 1: load X (7 rows x 4 cols), A1-mix, write P1^T ----------
    {
        float v[7][4];
        const float* xp = X + node0 * HID + c0;
#pragma unroll
        for (int i = 0; i < 7; ++i) {
            float4 t = *(const float4*)(xp + (long)i * HID);
            v[i][0] = t.x; v[i][1] = t.y; v[i][2] = t.z; v[i][3] = t.w;
        }
        mixA1(v);
        storePT(v, sh, g2, L);
    }
    // no barrier: wave reads only its own writes (in-wave ds ordering)

    // ---------- layer 1: acc = P1 @ W1 ----------
    float acc[7][4];
#pragma unroll
    for (int r = 0; r < 7; ++r)
#pragma unroll
        for (int j = 0; j < 4; ++j) acc[r][j] = 0.0f;
    gemm_k(acc, W1 + c0, sh, g2);

    {   // +b1, relu
        float4 bv = *(const float4*)(b1 + c0);
        const float bia[4] = {bv.x, bv.y, bv.z, bv.w};
#pragma unroll
        for (int r = 0; r < 7; ++r)
#pragma unroll
            for (int j = 0; j < 4; ++j)
                acc[r][j] = fmaxf(acc[r][j] + bia[j], 0.0f);
    }
    mixA1(acc);                 // P2 = A1 * H1
    storePT(acc, sh, g2, L);    // WAR vs own k-loop reads: in-wave order, safe

    // ---------- layer 2: acc = P2 @ W2 (same registers, never dual-live) ----------
#pragma unroll
    for (int r = 0; r < 7; ++r)
#pragma unroll
        for (int j = 0; j < 4; ++j) acc[r][j] = 0.0f;
    gemm_k(acc, W2 + c0, sh, g2);

    {   // +b2, relu
        float4 bv = *(const float4*)(b2 + c0);
        const float bia[4] = {bv.x, bv.y, bv.z, bv.w};
#pragma unroll
        for (int r = 0; r < 7; ++r)
#pragma unroll
            for (int j = 0; j < 4; ++j)
                acc[r][j] = fmaxf(acc[r][j] + bia[j], 0.0f);
    }

    // ---------- pm = (H2 @ Wm) partials over this lane's 4 cols ----------
    float pm[7][5];
#pragma unroll
    for (int r = 0; r < 7; ++r)
#pragma unroll
        for (int p = 0; p < 5; ++p) pm[r][p] = 0.0f;
#pragma unroll
    for (int j = 0; j < 4; ++j) {
        const float* wr = Wm + (c0 + j) * 5;
        float w[5];
#pragma unroll
        for (int p = 0; p < 5; ++p) w[p] = wr[p];
#pragma unroll
        for (int r = 0; r < 7; ++r)
#pragma unroll
            for (int p = 0; p < 5; ++p)
                pm[r][p] = fmaf(acc[r][j], w[p], pm[r][p]);
    }
    // full 64-lane butterfly (wave == one graph): every lane gets full sums
#pragma unroll
    for (int m = 32; m >= 1; m >>= 1)
#pragma unroll
        for (int r = 0; r < 7; ++r)
#pragma unroll
            for (int p = 0; p < 5; ++p)
                pm[r][p] += __shfl_xor(pm[r][p], m, 64);

    if (L < 7) {   // lane L finalizes node node0+L, all data in registers
        const int rr = L;
        const float d2r = d2c(rr);
        float op[5];
#pragma unroll
        for (int p = 0; p < 5; ++p) op[p] = bm[p];
#pragma unroll
        for (int i = 0; i < 7; ++i) {
            // A2 weight: self-loop d2r^2; incoming edge (i<rr) 0.5*d2[i]*d2r; else 0
            const float wgt = (i > rr) ? 0.0f
                            : (((i < rr) ? 0.5f : 1.0f) * d2c(i) * d2r);
#pragma unroll
            for (int p = 0; p < 5; ++p)
                op[p] = fmaf(wgt, pm[i][p], op[p]);
        }
        const float* gp = g_op + (node0 + rr) * 5;
        float best = op[0] + gp[0];
        int bi = 0;
#pragma unroll
        for (int p = 1; p < 5; ++p) {
            float u = op[p] + gp[p];
            if (u > best) { best = u; bi = p; }   // strict > == jnp.argmax first-max
        }
        float* o = out + (node0 + rr) * 5;
#pragma unroll
        for (int p = 0; p < 5; ++p) o[p] = (p == bi) ? 1.0f : 0.0f;
    }
}

extern "C" void kernel_launch(void* const* d_in, const int* in_sizes, int n_in,
                              void* d_out, int out_size, void* d_ws, size_t ws_size,
                              hipStream_t stream)
{
    const float* X   = (const float*)d_in[0];
    // d_in[1] edge_index, d_in[2] batch: compile-time-constant structure
    const float* W1  = (const float*)d_in[3];
    const float* b1  = (const float*)d_in[4];
    const float* W2  = (const float*)d_in[5];
    const float* b2  = (const float*)d_in[6];
    // d_in[7] We, d_in[8] be, d_in[11] g_edge: dead (avg_scores == 0.5)
    const float* Wm  = (const float*)d_in[9];
    const float* bm  = (const float*)d_in[10];
    const float* gop = (const float*)d_in[12];
    float* out = (float*)d_out;

    const int N       = in_sizes[0] / HID;  // 140000 nodes
    const int ngraph  = N / 7;              // 20000
    const int nblocks = ngraph / 4;         // 5000 blocks, 4 waves = 4 graphs

    nas_fused<<<nblocks, 256, 0, stream>>>(X, W1, b1, W2, b2, Wm, bm, gop, out);
}